// Round 1
// baseline (628.037 us; speedup 1.0000x reference)
//
#include <hip/hip_runtime.h>
#include <hip/hip_bf16.h>
#include <math.h>

// ---------------------------------------------------------------------------
// WindowMoBA, reduced form (see derivation):
//   out_pre[m,h,n,:] = 0.25 * sum_{tt<4} softmax(SCALE*q[tt*128+m/4,h] K[m%32,h]^T + bias_h) V[m%32,h]
//   out = out_pre @ w_proj + b_proj
// Gate/topk are dead code. K/V needed only for rows 0..1567 (kv groups 0..31).
// ---------------------------------------------------------------------------

#define N_TOK   49
#define DIMC    256
#define HEADS   8
#define HEAD_D  32
#define BWIN    512                  // B_ = BATCH*NUM_WIN
#define NKV     32                   // distinct K/V groups
#define MROWS   (BWIN * N_TOK)       // 25088
#define KVROWS  (NKV * N_TOK)        // 1568
#define SCALE_Q 0.17677669529663687f // 32^-0.5

// ---------------------------------------------------------------------------
// Generic fp32 GEMM tile: C[M x Ncols] = A[M x 256] @ W[256 x *](cols wcol0+)
// Tile 128x128, 256 threads, 8x8 per thread. A staged in LDS (XOR-swizzled
// column groups -> conflict-free ds_read_b128); W streamed from L2.
// ---------------------------------------------------------------------------
__device__ __forceinline__ void gemm_tile_128(
    const float* __restrict__ A, int M,
    const float* __restrict__ W, int ldw, int wcol0,
    const float* __restrict__ bias,
    float* __restrict__ C, int ldc,
    int mt, int nt, float* As /* 128*32 floats */)
{
    const int tid = threadIdx.x;
    const int tr  = tid >> 4;   // 0..15  (row group: rows tr*8..tr*8+7)
    const int tc  = tid & 15;   // 0..15  (col group: cols tc*8..tc*8+7)
    const int R0  = mt * 128;
    const int C0  = nt * 128;
    const int wc0 = wcol0 + C0 + tc * 8;

    float acc[8][8];
    #pragma unroll
    for (int j = 0; j < 8; ++j) {
        float bj = bias[wc0 + j];
        #pragma unroll
        for (int i = 0; i < 8; ++i) acc[i][j] = bj;
    }

    // K = 256 in 8 chunks of 32
    for (int kc = 0; kc < 8; ++kc) {
        if (kc) __syncthreads();
        // ---- stage A chunk: As[row][kk] (swizzled col-group), 1024 float4
        #pragma unroll
        for (int it = 0; it < 4; ++it) {
            int flat = it * 256 + tid;        // 0..1023
            int row  = flat >> 3;             // 0..127
            int q8   = flat & 7;              // float4 group in row
            int gr   = R0 + row; if (gr > M - 1) gr = M - 1;   // clamp (stores guarded)
            float4 v = *(const float4*)(A + (size_t)gr * 256 + kc * 32 + q8 * 4);
            int q8s  = q8 ^ ((row >> 3) & 7); // XOR swizzle: conflict-free frag reads
            *(float4*)(As + row * 32 + q8s * 4) = v;
        }
        __syncthreads();

        // ---- compute: 8 kk-quads
        #pragma unroll
        for (int kk4 = 0; kk4 < 8; ++kk4) {
            float a[8][4];
            const int cg = (kk4 ^ (tr & 7)) << 2;   // de-swizzle
            #pragma unroll
            for (int i = 0; i < 8; ++i) {
                float4 t = *(const float4*)(As + (tr * 8 + i) * 32 + cg);
                a[i][0] = t.x; a[i][1] = t.y; a[i][2] = t.z; a[i][3] = t.w;
            }
            #pragma unroll
            for (int dk = 0; dk < 4; ++dk) {
                const float* wp = W + (size_t)(kc * 32 + kk4 * 4 + dk) * ldw + wc0;
                float4 w0 = *(const float4*)(wp);
                float4 w1 = *(const float4*)(wp + 4);
                float wv[8] = {w0.x, w0.y, w0.z, w0.w, w1.x, w1.y, w1.z, w1.w};
                #pragma unroll
                for (int i = 0; i < 8; ++i) {
                    float av = a[i][dk];
                    #pragma unroll
                    for (int j = 0; j < 8; ++j)
                        acc[i][j] = fmaf(av, wv[j], acc[i][j]);
                }
            }
        }
    }

    // ---- store
    #pragma unroll
    for (int i = 0; i < 8; ++i) {
        int gr = R0 + tr * 8 + i;
        if (gr < M) {
            float* cp = C + (size_t)gr * ldc + C0 + tc * 8;
            float4 s0 = {acc[i][0], acc[i][1], acc[i][2], acc[i][3]};
            float4 s1 = {acc[i][4], acc[i][5], acc[i][6], acc[i][7]};
            *(float4*)(cp)     = s0;
            *(float4*)(cp + 4) = s1;
        }
    }
}

// QKV: blocks 0..391 -> Q (M=25088, W cols 0..255 -> qbuf ldc 256)
//      blocks 392..443 -> KV (M=1568, W cols 256..767 -> kvbuf ldc 512)
__global__ __launch_bounds__(256) void k_gemm_qkv(
    const float* __restrict__ x, const float* __restrict__ w,
    const float* __restrict__ b, float* __restrict__ qbuf,
    float* __restrict__ kvbuf)
{
    __shared__ float As[128 * 32];
    int bx = blockIdx.x;
    if (bx < 392) {
        gemm_tile_128(x, MROWS, w, 768, 0,   b, qbuf,  256, bx >> 1, bx & 1, As);
    } else {
        int b2 = bx - 392;     // 13 mt x 4 nt
        gemm_tile_128(x, KVROWS, w, 768, 256, b, kvbuf, 512, b2 >> 2, b2 & 3, As);
    }
}

__global__ __launch_bounds__(256) void k_gemm_proj(
    const float* __restrict__ ob, const float* __restrict__ w,
    const float* __restrict__ b, float* __restrict__ out)
{
    __shared__ float As[128 * 32];
    gemm_tile_128(ob, MROWS, w, 256, 0, b, out, 256, blockIdx.x >> 1, blockIdx.x & 1, As);
}

// ---------------------------------------------------------------------------
// Attention: one wave per (m, h). lane = query row (49 used, 15 clamped).
// K/V/bias-table addresses are wave-uniform -> compiler may scalarize (s_load),
// keeping VALU as the bound. Softmax fully in-lane. 1/4-mean folded in.
// ---------------------------------------------------------------------------
__global__ __launch_bounds__(64) void k_attn(
    const float* __restrict__ qbuf,   // (25088, 256)
    const float* __restrict__ kvbuf,  // (1568, 512): cols 0..255 K, 256..511 V
    const float* __restrict__ table,  // (169, 8)
    float* __restrict__ obuf)         // (25088, 256)
{
    const int m    = blockIdx.x;          // 0..511
    const int h    = blockIdx.y;          // 0..7
    const int lane = threadIdx.x;         // 0..63
    const int r    = lane < 49 ? lane : 48;
    const int kv   = m & 31;

    // relative-position bias row for this query row, in registers
    float bias[49];
    const int rh = r / 7, rw = r % 7;
    #pragma unroll
    for (int j = 0; j < 49; ++j) {
        const int jh = j / 7, jw = j % 7;             // compile-time
        const int idx = (rh - jh + 6) * 13 + (rw - jw + 6);
        bias[j] = table[idx * HEADS + h];
    }

    float o[32];
    #pragma unroll
    for (int d = 0; d < 32; ++d) o[d] = 0.f;

    const float* kbase = kvbuf + (size_t)(kv * 49) * 512 + h * 32;
    const float* vbase = kbase + 256;

    for (int tt = 0; tt < 4; ++tt) {
        const int qidx = tt * 128 + (m >> 2);
        const float* qp = qbuf + ((size_t)qidx * 49 + r) * 256 + h * 32;
        float q[32];
        #pragma unroll
        for (int d4 = 0; d4 < 8; ++d4) {
            float4 t = *(const float4*)(qp + d4 * 4);
            q[d4*4+0] = t.x * SCALE_Q; q[d4*4+1] = t.y * SCALE_Q;
            q[d4*4+2] = t.z * SCALE_Q; q[d4*4+3] = t.w * SCALE_Q;
        }

        float s[49];
        #pragma unroll
        for (int j = 0; j < 49; ++j) {
            const float* kp = kbase + j * 512;        // wave-uniform
            float a0 = 0.f, a1 = 0.f, a2 = 0.f, a3 = 0.f;
            #pragma unroll
            for (int d4 = 0; d4 < 8; ++d4) {
                float4 k4 = *(const float4*)(kp + d4 * 4);
                a0 = fmaf(q[d4*4+0], k4.x, a0);
                a1 = fmaf(q[d4*4+1], k4.y, a1);
                a2 = fmaf(q[d4*4+2], k4.z, a2);
                a3 = fmaf(q[d4*4+3], k4.w, a3);
            }
            s[j] = (a0 + a1) + (a2 + a3) + bias[j];
        }

        // in-lane softmax over 49 values
        float mx = s[0];
        #pragma unroll
        for (int j = 1; j < 49; ++j) mx = fmaxf(mx, s[j]);
        float sum = 0.f;
        #pragma unroll
        for (int j = 0; j < 49; ++j) { s[j] = __expf(s[j] - mx); sum += s[j]; }
        const float inv = 1.0f / sum;
        #pragma unroll
        for (int j = 0; j < 49; ++j) s[j] *= inv;

        // PV
        #pragma unroll
        for (int j = 0; j < 49; ++j) {
            const float* vp = vbase + j * 512;        // wave-uniform
            const float pj = s[j];
            #pragma unroll
            for (int d4 = 0; d4 < 8; ++d4) {
                float4 v4 = *(const float4*)(vp + d4 * 4);
                o[d4*4+0] = fmaf(pj, v4.x, o[d4*4+0]);
                o[d4*4+1] = fmaf(pj, v4.y, o[d4*4+1]);
                o[d4*4+2] = fmaf(pj, v4.z, o[d4*4+2]);
                o[d4*4+3] = fmaf(pj, v4.w, o[d4*4+3]);
            }
        }
    }

    if (lane < 49) {
        float* op = obuf + ((size_t)m * 49 + lane) * 256 + h * 32;
        #pragma unroll
        for (int d4 = 0; d4 < 8; ++d4) {
            float4 t = {o[d4*4+0] * 0.25f, o[d4*4+1] * 0.25f,
                        o[d4*4+2] * 0.25f, o[d4*4+3] * 0.25f};
            *(float4*)(op + d4 * 4) = t;
        }
    }
}

// ---------------------------------------------------------------------------
extern "C" void kernel_launch(void* const* d_in, const int* in_sizes, int n_in,
                              void* d_out, int out_size, void* d_ws, size_t ws_size,
                              hipStream_t stream)
{
    const float* x      = (const float*)d_in[0];
    const float* w_qkv  = (const float*)d_in[1];
    const float* b_qkv  = (const float*)d_in[2];
    const float* table  = (const float*)d_in[3];
    const float* w_proj = (const float*)d_in[4];
    const float* b_proj = (const float*)d_in[5];
    float* out = (float*)d_out;

    // workspace: qbuf 25088x256 | kvbuf 1568x512 | obuf 25088x256  (54.6 MB)
    float* qbuf  = (float*)d_ws;
    float* kvbuf = qbuf + (size_t)MROWS * 256;
    float* obuf  = kvbuf + (size_t)KVROWS * 512;

    k_gemm_qkv<<<444, 256, 0, stream>>>(x, w_qkv, b_qkv, qbuf, kvbuf);
    k_attn<<<dim3(512, 8), 64, 0, stream>>>(qbuf, kvbuf, table, obuf);
    k_gemm_proj<<<392, 256, 0, stream>>>(obuf, w_proj, b_proj, out);
}